// Round 1
// baseline (870.114 us; speedup 1.0000x reference)
//
#include <hip/hip_runtime.h>

typedef __bf16 bf16_t;
typedef __bf16 bf16x8 __attribute__((ext_vector_type(8)));
typedef __bf16 bf16x4 __attribute__((ext_vector_type(4)));
typedef float f32x4 __attribute__((ext_vector_type(4)));

#define SCALE 0.17677669529663687f

__device__ __forceinline__ f32x4 mfma16(bf16x8 a, bf16x8 b, f32x4 c) {
  return __builtin_amdgcn_mfma_f32_16x16x32_bf16(a, b, c, 0, 0, 0);
}

// ws layout (bf16 elements): q_wb [0,36864), kv_wb [36864,110592), proj_wb [110592,147456)
__global__ void prep_weights(const float* __restrict__ qw,
                             const float* __restrict__ kvw,
                             const float* __restrict__ pw,
                             bf16_t* __restrict__ wsb) {
  int i = blockIdx.x * 256 + threadIdx.x;  // 36864 threads, 4 elems each
#pragma unroll
  for (int j = 0; j < 4; ++j) {
    int e = i * 4 + j;
    float v;
    if (e < 36864) v = qw[e];
    else if (e < 110592) v = kvw[e - 36864];
    else v = pw[e - 110592];
    wsb[e] = (bf16_t)v;
  }
}

template <bool WS>
__device__ __forceinline__ bf16x8 ldw(const bf16_t* __restrict__ wb,
                                      const float* __restrict__ wf, int off) {
  if constexpr (WS) {
    return *(const bf16x8*)(wb + off);
  } else {
    const float4* p = (const float4*)(wf + off);
    float4 a = p[0], c = p[1];
    bf16x8 r;
    r[0] = (bf16_t)a.x; r[1] = (bf16_t)a.y; r[2] = (bf16_t)a.z; r[3] = (bf16_t)a.w;
    r[4] = (bf16_t)c.x; r[5] = (bf16_t)c.y; r[6] = (bf16_t)c.z; r[7] = (bf16_t)c.w;
    return r;
  }
}

// One block = one window. 512 threads = 8 waves.
// LDS (bytes):
//   x1s  @      0  [64][200] bf16  (aliased later: atts)
//   x2s  @  25600  [64][200] bf16  (aliased later: ps[2][64][72])
//   qs   @  51200  [64][200] bf16
//   ks   @  76800  [64][200] bf16
//   vts  @ 102400  [192][72] bf16   total 130048
template <bool WS>
__global__ __launch_bounds__(512, 2) void wca_main(
    const float* __restrict__ x1, const float* __restrict__ x2,
    const float* __restrict__ mask,
    const float* __restrict__ qw_f, const float* __restrict__ qb,
    const float* __restrict__ kvw_f, const float* __restrict__ kvb,
    const float* __restrict__ pw_f, const float* __restrict__ pb,
    const float* __restrict__ table,
    const bf16_t* __restrict__ wsb,
    float* __restrict__ out) {
  extern __shared__ char smem[];
  bf16_t* x1s = (bf16_t*)smem;             // [64][200]
  bf16_t* x2s = (bf16_t*)(smem + 25600);   // [64][200]
  bf16_t* qs  = (bf16_t*)(smem + 51200);   // [64][200]
  bf16_t* ks  = (bf16_t*)(smem + 76800);   // [64][200]
  bf16_t* vts = (bf16_t*)(smem + 102400);  // [192][72]
  bf16_t* ps  = x2s;                       // [2][64][72] (per head-half)
  bf16_t* atts = x1s;                      // [64][200]

  const int t = threadIdx.x;
  const int w = t >> 6;
  const int l = t & 63;
  const int lo = l & 15;
  const int hi = l >> 4;
  const int b = blockIdx.x;

  const bf16_t* q_wb = wsb;
  const bf16_t* kv_wb = wsb + 36864;
  const bf16_t* p_wb = wsb + 110592;

  // ---------- phase 1: stage x1, x2 (f32 -> bf16 LDS) ----------
  {
    const float4* s1 = (const float4*)(x1 + (size_t)b * 12288);
    const float4* s2 = (const float4*)(x2 + (size_t)b * 12288);
#pragma unroll
    for (int it = 0; it < 6; ++it) {
      int idx = it * 512 + t;  // 0..3071 = 64 rows x 48 float4
      int n = idx / 48, c4 = idx % 48;
      float4 v = s1[idx];
      bf16x4 pk1;
      pk1[0] = (bf16_t)v.x; pk1[1] = (bf16_t)v.y; pk1[2] = (bf16_t)v.z; pk1[3] = (bf16_t)v.w;
      *(bf16x4*)(x1s + n * 200 + c4 * 4) = pk1;
      float4 u = s2[idx];
      bf16x4 pk2;
      pk2[0] = (bf16_t)u.x; pk2[1] = (bf16_t)u.y; pk2[2] = (bf16_t)u.z; pk2[3] = (bf16_t)u.w;
      *(bf16x4*)(x2s + n * 200 + c4 * 4) = pk2;
    }
  }
  __syncthreads();

  // ---------- phase 2: Q proj (waves 0-3) | KV proj (waves 4-7) ----------
  if (w < 4) {
    // Q: out cols w*48 .. w*48+47  (3 col-tiles x 4 row-tiles), K=192
    f32x4 acc[4][3];
#pragma unroll
    for (int rt = 0; rt < 4; ++rt)
#pragma unroll
      for (int ct = 0; ct < 3; ++ct) { f32x4 z = {0.f,0.f,0.f,0.f}; acc[rt][ct] = z; }
#pragma unroll
    for (int kk = 0; kk < 6; ++kk) {
      bf16x8 a[4];
#pragma unroll
      for (int rt = 0; rt < 4; ++rt)
        a[rt] = *(const bf16x8*)(x1s + (rt * 16 + lo) * 200 + kk * 32 + hi * 8);
      bf16x8 bw[3];
#pragma unroll
      for (int ct = 0; ct < 3; ++ct) {
        int col = w * 48 + ct * 16 + lo;
        bw[ct] = ldw<WS>(q_wb, qw_f, col * 192 + kk * 32 + hi * 8);
      }
#pragma unroll
      for (int rt = 0; rt < 4; ++rt)
#pragma unroll
        for (int ct = 0; ct < 3; ++ct)
          acc[rt][ct] = mfma16(a[rt], bw[ct], acc[rt][ct]);
    }
#pragma unroll
    for (int ct = 0; ct < 3; ++ct) {
      int col = w * 48 + ct * 16 + lo;
      float bv = qb[col];
#pragma unroll
      for (int rt = 0; rt < 4; ++rt)
#pragma unroll
        for (int i = 0; i < 4; ++i)
          qs[(rt * 16 + hi * 4 + i) * 200 + col] = (bf16_t)((acc[rt][ct][i] + bv) * SCALE);
    }
  } else {
    // KV: kw 0,1 -> K cols 0-95 / 96-191 ; kw 2,3 -> V cols 0-95 / 96-191
    const int kw = w - 4;
    const int part = kw >> 1;            // 0 = K, 1 = V
    const int halfo = (kw & 1) * 96;
    f32x4 acc[4][6];
#pragma unroll
    for (int rt = 0; rt < 4; ++rt)
#pragma unroll
      for (int ct = 0; ct < 6; ++ct) { f32x4 z = {0.f,0.f,0.f,0.f}; acc[rt][ct] = z; }
#pragma unroll
    for (int kk = 0; kk < 6; ++kk) {
      bf16x8 a[4];
#pragma unroll
      for (int rt = 0; rt < 4; ++rt)
        a[rt] = *(const bf16x8*)(x2s + (rt * 16 + lo) * 200 + kk * 32 + hi * 8);
      bf16x8 bw[6];
#pragma unroll
      for (int ct = 0; ct < 6; ++ct) {
        int row = part * 192 + halfo + ct * 16 + lo;
        bw[ct] = ldw<WS>(kv_wb, kvw_f, row * 192 + kk * 32 + hi * 8);
      }
#pragma unroll
      for (int rt = 0; rt < 4; ++rt)
#pragma unroll
        for (int ct = 0; ct < 6; ++ct)
          acc[rt][ct] = mfma16(a[rt], bw[ct], acc[rt][ct]);
    }
#pragma unroll
    for (int ct = 0; ct < 6; ++ct) {
      int och = halfo + ct * 16 + lo;
      float bv = kvb[part * 192 + och];
      if (part == 0) {
#pragma unroll
        for (int rt = 0; rt < 4; ++rt)
#pragma unroll
          for (int i = 0; i < 4; ++i)
            ks[(rt * 16 + hi * 4 + i) * 200 + och] = (bf16_t)(acc[rt][ct][i] + bv);
      } else {
        // write V transposed: vts[channel][n]
#pragma unroll
        for (int rt = 0; rt < 4; ++rt) {
          int n0 = rt * 16 + hi * 4;
          bf16x4 pk;
#pragma unroll
          for (int i = 0; i < 4; ++i) pk[i] = (bf16_t)(acc[rt][ct][i] + bv);
          *(bf16x4*)(vts + och * 72 + n0) = pk;
        }
      }
    }
  }
  __syncthreads();

  // ---------- phase 3: attention. wave = (rowtile rt3 = w>>1, head-half hh = w&1) ----------
  {
    const int rt3 = w >> 1;
    const int hh = w & 1;
    const int rbase = rt3 * 16;
    bf16_t* psw = ps + hh * 4608;  // [64][72]
    const float* maskp = mask + (size_t)(b & 1023) * 4096;
    int relidx[4][4];
    float mval[4][4];
#pragma unroll
    for (int i = 0; i < 4; ++i) {
      int r = rbase + hi * 4 + i;
      int ih = r >> 3, iw = r & 7;
#pragma unroll
      for (int ct = 0; ct < 4; ++ct) {
        int c = ct * 16 + lo;
        int jh = c >> 3, jw = c & 7;
        relidx[i][ct] = ((ih - jh + 7) * 15 + (iw - jw + 7)) * 6;
        mval[i][ct] = maskp[r * 64 + c];
      }
    }
    for (int hq = 0; hq < 3; ++hq) {
      const int h = hh * 3 + hq;
      bf16x8 qa = *(const bf16x8*)(qs + (rbase + lo) * 200 + h * 32 + hi * 8);
      f32x4 s[4];
#pragma unroll
      for (int ct = 0; ct < 4; ++ct) {
        bf16x8 kb = *(const bf16x8*)(ks + (ct * 16 + lo) * 200 + h * 32 + hi * 8);
        f32x4 z = {0.f, 0.f, 0.f, 0.f};
        s[ct] = mfma16(qa, kb, z);
      }
      float m4[4] = {-1e30f, -1e30f, -1e30f, -1e30f};
#pragma unroll
      for (int ct = 0; ct < 4; ++ct)
#pragma unroll
        for (int i = 0; i < 4; ++i) {
          float sv = s[ct][i] + table[relidx[i][ct] + h] + mval[i][ct];
          s[ct][i] = sv;
          m4[i] = fmaxf(m4[i], sv);
        }
#pragma unroll
      for (int d = 1; d < 16; d <<= 1)
#pragma unroll
        for (int i = 0; i < 4; ++i)
          m4[i] = fmaxf(m4[i], __shfl_xor(m4[i], d));
      float sm[4] = {0.f, 0.f, 0.f, 0.f};
#pragma unroll
      for (int ct = 0; ct < 4; ++ct)
#pragma unroll
        for (int i = 0; i < 4; ++i) {
          float p = __expf(s[ct][i] - m4[i]);
          s[ct][i] = p;
          sm[i] += p;
        }
#pragma unroll
      for (int d = 1; d < 16; d <<= 1)
#pragma unroll
        for (int i = 0; i < 4; ++i)
          sm[i] += __shfl_xor(sm[i], d);
      // write P (unnormalized) to LDS for A-fragment reads
#pragma unroll
      for (int ct = 0; ct < 4; ++ct)
#pragma unroll
        for (int i = 0; i < 4; ++i)
          psw[(rbase + hi * 4 + i) * 72 + ct * 16 + lo] = (bf16_t)s[ct][i];
      // PV
      f32x4 o0 = {0.f, 0.f, 0.f, 0.f}, o1 = {0.f, 0.f, 0.f, 0.f};
#pragma unroll
      for (int k2 = 0; k2 < 2; ++k2) {
        bf16x8 pa = *(const bf16x8*)(psw + (rbase + lo) * 72 + k2 * 32 + hi * 8);
        bf16x8 v0 = *(const bf16x8*)(vts + (h * 32 + lo) * 72 + k2 * 32 + hi * 8);
        bf16x8 v1 = *(const bf16x8*)(vts + (h * 32 + 16 + lo) * 72 + k2 * 32 + hi * 8);
        o0 = mfma16(pa, v0, o0);
        o1 = mfma16(pa, v1, o1);
      }
#pragma unroll
      for (int i = 0; i < 4; ++i) {
        float rinv = 1.0f / sm[i];
        int r = rbase + hi * 4 + i;
        atts[r * 200 + h * 32 + lo] = (bf16_t)(o0[i] * rinv);
        atts[r * 200 + h * 32 + 16 + lo] = (bf16_t)(o1[i] * rinv);
      }
    }
  }
  __syncthreads();

  // ---------- phase 4: out proj. wave = (rowtile w&3, col-group w>>2) ----------
  {
    const int rt4 = w & 3;
    const int cg = w >> 2;
    f32x4 acc[6];
#pragma unroll
    for (int ct = 0; ct < 6; ++ct) { f32x4 z = {0.f,0.f,0.f,0.f}; acc[ct] = z; }
#pragma unroll
    for (int kk = 0; kk < 6; ++kk) {
      bf16x8 a = *(const bf16x8*)(atts + (rt4 * 16 + lo) * 200 + kk * 32 + hi * 8);
      bf16x8 bw[6];
#pragma unroll
      for (int ct = 0; ct < 6; ++ct) {
        int col = cg * 96 + ct * 16 + lo;
        bw[ct] = ldw<WS>(p_wb, pw_f, col * 192 + kk * 32 + hi * 8);
      }
#pragma unroll
      for (int ct = 0; ct < 6; ++ct)
        acc[ct] = mfma16(a, bw[ct], acc[ct]);
    }
    float* outp = out + (size_t)b * 12288;
#pragma unroll
    for (int ct = 0; ct < 6; ++ct) {
      int col = cg * 96 + ct * 16 + lo;
      float bv = pb[col];
#pragma unroll
      for (int i = 0; i < 4; ++i)
        outp[(rt4 * 16 + hi * 4 + i) * 192 + col] = acc[ct][i] + bv;
    }
  }
}

extern "C" void kernel_launch(void* const* d_in, const int* in_sizes, int n_in,
                              void* d_out, int out_size, void* d_ws, size_t ws_size,
                              hipStream_t stream) {
  const float* x1 = (const float*)d_in[0];
  const float* x2 = (const float*)d_in[1];
  const float* mask = (const float*)d_in[2];
  const float* qw = (const float*)d_in[3];
  const float* qb = (const float*)d_in[4];
  const float* kvw = (const float*)d_in[5];
  const float* kvb = (const float*)d_in[6];
  const float* pw = (const float*)d_in[7];
  const float* pb = (const float*)d_in[8];
  const float* table = (const float*)d_in[9];
  float* out = (float*)d_out;
  bf16_t* wsb = (bf16_t*)d_ws;
  const int LDS_BYTES = 130048;
  if (ws_size >= 294912) {
    prep_weights<<<144, 256, 0, stream>>>(qw, kvw, pw, wsb);
    wca_main<true><<<8192, 512, LDS_BYTES, stream>>>(x1, x2, mask, qw, qb, kvw, kvb,
                                                     pw, pb, table, wsb, out);
  } else {
    wca_main<false><<<8192, 512, LDS_BYTES, stream>>>(x1, x2, mask, qw, qb, kvw, kvb,
                                                      pw, pb, table, wsb, out);
  }
}